// Round 9
// baseline (75.731 us; speedup 1.0000x reference)
//
#include <hip/hip_runtime.h>
#include <math.h>

namespace {

constexpr int   kN       = 4096;
constexpr int   kThreads = 256;              // 4 waves/block, 1 query/wave
constexpr int   kGroups  = 32;               // f16x2 groups per lane (64 elems/lane)
constexpr int   kIters   = 9;                // bracket [0,32768] -> width 64 (d2 0.031)
constexpr float kM0      = 0.3f;
constexpr float kS       = 2048.f;           // d2 scale: 16*2048 = 32768 < f16 max
constexpr float kRootS   = 45.25483399593904f;  // sqrt(2048)

typedef _Float16 h2 __attribute__((ext_vector_type(2)));

// 1-inst f32x2 -> f16x2 (v_cvt_pkrtz_f16_f32); bit_cast bridges __fp16x2 -> h2.
__device__ __forceinline__ h2 pkrtz(float a, float b) {
    return __builtin_bit_cast(h2, __builtin_amdgcn_cvt_pkrtz(a, b));
}

// DPP wave-64 sum -> uniform scalar (readlane 63): VALU-pipe only.
__device__ __forceinline__ float dppAdd_(float x, int t) {
    return x + __builtin_bit_cast(float, t);
}
__device__ __forceinline__ float waveSumUniform(float x) {
    int xi;
    xi = __builtin_amdgcn_update_dpp(0, __builtin_bit_cast(int, x), 0x111, 0xf, 0xf, true);
    x  = dppAdd_(x, xi);   // row_shr:1
    xi = __builtin_amdgcn_update_dpp(0, __builtin_bit_cast(int, x), 0x112, 0xf, 0xf, true);
    x  = dppAdd_(x, xi);   // row_shr:2
    xi = __builtin_amdgcn_update_dpp(0, __builtin_bit_cast(int, x), 0x114, 0xf, 0xf, true);
    x  = dppAdd_(x, xi);   // row_shr:4
    xi = __builtin_amdgcn_update_dpp(0, __builtin_bit_cast(int, x), 0x118, 0xf, 0xf, true);
    x  = dppAdd_(x, xi);   // row_shr:8  -> lane15 of each row = row sum
    xi = __builtin_amdgcn_update_dpp(0, __builtin_bit_cast(int, x), 0x142, 0xa, 0xf, true);
    x  = dppAdd_(x, xi);   // row_bcast15
    xi = __builtin_amdgcn_update_dpp(0, __builtin_bit_cast(int, x), 0x143, 0xc, 0xf, true);
    x  = dppAdd_(x, xi);   // row_bcast31 -> lane63 = total
    return __builtin_bit_cast(float, __builtin_amdgcn_readlane(__builtin_bit_cast(int, x), 63));
}

// ONE instruction for clamp01(m - d): VOP3P neg modifier on src1 + CLAMP bit.
// (Compiler emits 3 insts for the min/max/sub idiom; the ISA does it in 1.)
__device__ __forceinline__ h2 subClamp01(h2 m, h2 d) {
    h2 r;
    asm("v_pk_add_f16 %0, %1, %2 neg_lo:[0,1] neg_hi:[0,1] clamp"
        : "=v"(r) : "v"(m), "v"(d));
    return r;
}

// 1 query/wave: d2s+ws = 64 array VGPRs (vs 96 for 2q/wave) -> no AGPR
// pressure, ~5 waves/SIMD. Bisection mids are multiples of 64 <= 32768 ->
// exact in f16; final-pass mask at lo is bitwise-consistent with T(lo),
// preserving T(lo) < wb <= T(hi). W comes free as the tracked Tlo.
__global__ __launch_bounds__(kThreads, 4)
void dtm_kernel(const float* __restrict__ input,   // (B, N, 2)
                const float* __restrict__ weight,  // (B, N)
                const float* __restrict__ grid,    // (N, 2)
                float* __restrict__ out,           // (B, N)
                int nq) {
    const int lane = threadIdx.x & 63;
    const int wave = threadIdx.x >> 6;
    const int q = blockIdx.x * 4 + wave;
    if (q >= nq) return;
    const int b = q >> 12;
    const int i = q & (kN - 1);

    const float sgx = kRootS * grid[2 * i];      // wave-uniform -> scalar loads
    const float sgy = kRootS * grid[2 * i + 1];
    const float4* inp4 = (const float4*)(input + (size_t)b * kN * 2);
    const float4* wgt4 = (const float4*)(weight + (size_t)b * kN);

    const h2 one2 = h2{(_Float16)1.f, (_Float16)1.f};

    h2 d2s[kGroups], ws[kGroups];                // 64 VGPRs; d2s holds 2048*d2
    float wl = 0.f;
#pragma unroll
    for (int s = 0; s < kGroups / 2; ++s) {      // 4 elements per trip
        const int g = lane + 64 * s;
        const float4 wv = wgt4[g];
        const float4 pa = inp4[2 * g];
        const float4 pb = inp4[2 * g + 1];
        float dx, dy, e0, e1, e2, e3;
        dx = fmaf(-kRootS, pa.x, sgx); dy = fmaf(-kRootS, pa.y, sgy); e0 = fmaf(dy, dy, dx * dx);
        dx = fmaf(-kRootS, pa.z, sgx); dy = fmaf(-kRootS, pa.w, sgy); e1 = fmaf(dy, dy, dx * dx);
        dx = fmaf(-kRootS, pb.x, sgx); dy = fmaf(-kRootS, pb.y, sgy); e2 = fmaf(dy, dy, dx * dx);
        dx = fmaf(-kRootS, pb.z, sgx); dy = fmaf(-kRootS, pb.w, sgy); e3 = fmaf(dy, dy, dx * dx);
        d2s[2 * s]     = pkrtz(e0, e1);          // 1-inst f32x2 -> f16x2
        d2s[2 * s + 1] = pkrtz(e2, e3);
        ws[2 * s]      = pkrtz(wv.x, wv.y);
        ws[2 * s + 1]  = pkrtz(wv.z, wv.w);
        wl = __builtin_amdgcn_fdot2(ws[2 * s],     one2, wl, false);
        wl = __builtin_amdgcn_fdot2(ws[2 * s + 1], one2, wl, false);
        // Scheduling fence every 2 trips: stops the compiler hoisting all 48
        // float4 loads to the top (register-pressure blow-up seen in R3/R7).
        if ((s & 1) == 1) asm volatile("" ::: "memory");
    }
    const float wb = kM0 * waveSumUniform(wl);

    // Bisection; all bracket state is uniform scalar (SALU compare/update).
    float lo = 0.f, hi = 32768.f, Tlo = 0.f;
#pragma unroll
    for (int it = 0; it < kIters; ++it) {
        const float mid = 0.5f * (lo + hi);
        const _Float16 mh = (_Float16)mid;       // exact (multiple of 64)
        const h2 mid2 = h2{mh, mh};
        float a0 = 0.f, a1 = 0.f;
#pragma unroll
        for (int g = 0; g < kGroups; g += 2) {
            const h2 t0 = subClamp01(mid2, d2s[g]);
            const h2 t1 = subClamp01(mid2, d2s[g + 1]);
            a0 = __builtin_amdgcn_fdot2(ws[g],     t0, a0, false);
            a1 = __builtin_amdgcn_fdot2(ws[g + 1], t1, a1, false);
        }
        const float T = waveSumUniform(a0 + a1);
        if (T >= wb) hi = mid; else { lo = mid; Tlo = T; }
    }

    // Final pass: A = sum(d2*w) below lo with the IDENTICAL mask; W = Tlo.
    {
        const _Float16 lh = (_Float16)lo;        // exact
        const h2 lo2 = h2{lh, lh};
        float A0 = 0.f, A1 = 0.f;
#pragma unroll
        for (int g = 0; g < kGroups; g += 2) {
            const h2 t0 = subClamp01(lo2, d2s[g]);
            const h2 t1 = subClamp01(lo2, d2s[g + 1]);
            const h2 p0 = d2s[g] * ws[g];        // scaled d2*w <= 32768 < 65504
            const h2 p1 = d2s[g + 1] * ws[g + 1];
            A0 = __builtin_amdgcn_fdot2(p0, t0, A0, false);
            A1 = __builtin_amdgcn_fdot2(p1, t1, A1, false);
        }
        const float A = waveSumUniform(A0 + A1);
        if (lane == 0) {
            const float dtm = (A + hi * (wb - Tlo)) * (1.f / kS);
            out[q] = sqrtf(fmaxf(dtm, 0.f) / wb);
        }
    }
}

}  // namespace

extern "C" void kernel_launch(void* const* d_in, const int* in_sizes, int n_in,
                              void* d_out, int out_size, void* d_ws, size_t ws_size,
                              hipStream_t stream) {
    const float* input  = (const float*)d_in[0];   // (B, N, 2) f32
    const float* weight = (const float*)d_in[1];   // (B, N)    f32
    const float* grid   = (const float*)d_in[2];   // (N, 2)    f32
    float* out = (float*)d_out;                    // (B, N)    f32
    const int nq = out_size;                       // B * N = 8192
    const int blocks = (nq + 3) / 4;               // 1 query/wave, 4 waves/block
    dtm_kernel<<<dim3(blocks), dim3(kThreads), 0, stream>>>(input, weight, grid, out, nq);
}